// Round 1
// 4355.264 us; speedup vs baseline: 1.0576x; 1.0576x over previous
//
#include <hip/hip_runtime.h>
#include <hip/hip_bf16.h>
#include <stdint.h>

typedef unsigned int uint;
typedef unsigned short ushort;

#define SEQ   2048
#define TGT   1024
#define HDIM  256
#define IN3   288
#define G3    768
#define NHIST 4096
#define DL    256
#define DT    32
#define DU    64
#define NLOC  100000
#define DOUT  1088

typedef short short8 __attribute__((ext_vector_type(8)));
typedef float floatx4 __attribute__((ext_vector_type(4)));
typedef float float4v __attribute__((ext_vector_type(4)));
typedef ushort ushort8v __attribute__((ext_vector_type(8)));
typedef _Float16 half8v __attribute__((ext_vector_type(8)));

__device__ __forceinline__ ushort f2bf(float f) {
  uint u = __builtin_bit_cast(uint, f);
  u += 0x7FFFu + ((u >> 16) & 1u);
  return (ushort)(u >> 16);
}

// ---------------- pack Whh (f32 row-major 768x256) into MFMA A-fragment layout ----------------
// Layout: wpack[dir][wave(8)][rt(6)][kt(8)][lane(64)] = uint4 (8 f16)
// A-fragment mapping for mfma_f32_16x16x32_f16: row = wave*96 + rt*16 + (lane&15),
// k = kt*32 + (lane>>4)*8 + j  (j = 0..7)
__global__ void k_pack_whh(const float* __restrict__ whf, const float* __restrict__ whb,
                           uint4* __restrict__ wpack) {
  int idx = blockIdx.x * 256 + threadIdx.x;  // 0 .. 49151
  int dir = idx / 24576;
  int r = idx - dir * 24576;
  int wave = r / 3072;
  int r2 = r - wave * 3072;
  int rt = r2 / 512;
  int r3 = r2 - rt * 512;
  int kt = r3 / 64;
  int lane = r3 - kt * 64;
  int row = wave * 96 + rt * 16 + (lane & 15);
  int kb = kt * 32 + (lane >> 4) * 8;
  const float* W = dir ? whb : whf;
  const float* src = W + (size_t)row * 256 + kb;
  half8v h;
  #pragma unroll
  for (int j = 0; j < 8; ++j) h[j] = (_Float16)src[j];
  wpack[idx] = __builtin_bit_cast(uint4, h);
}

// ---------------- x = [emb_loc[loc], emb_tim[tim]] as bf16 ----------------
__global__ void k_embed_x(const int* __restrict__ loc, const int* __restrict__ tim,
                          const float* __restrict__ emb_loc, const float* __restrict__ emb_tim,
                          ushort* __restrict__ xb) {
  int t = blockIdx.x;
  int tid = threadIdx.x;
  int l = loc[t], m = tim[t];
  if (tid < 256) xb[(size_t)t * IN3 + tid] = f2bf(emb_loc[(size_t)l * DL + tid]);
  if (tid < 32)  xb[(size_t)t * IN3 + 256 + tid] = f2bf(emb_tim[m * DT + tid]);
}

// ---------------- exclusive prefix sum of 4096 counts ----------------
__global__ void k_scan(const int* __restrict__ counts, int* __restrict__ offs) {
  __shared__ int sd[1024];
  int tid = threadIdx.x;
  int base = tid * 4;
  int c0 = counts[base], c1 = counts[base + 1], c2 = counts[base + 2], c3 = counts[base + 3];
  int tot = c0 + c1 + c2 + c3;
  sd[tid] = tot;
  __syncthreads();
  int val = tot;
  for (int off = 1; off < 1024; off <<= 1) {
    int v = (tid >= off) ? sd[tid - off] : 0;
    __syncthreads();
    val += v;
    sd[tid] = val;
    __syncthreads();
  }
  int excl = val - tot;
  offs[base] = excl;
  offs[base + 1] = excl + c0;
  offs[base + 2] = excl + c0 + c1;
  offs[base + 3] = excl + c0 + c1 + c2;
}

// ---------------- Hin = [segment_mean(emb_loc), emb_tim[first]] as bf16 ----------------
__global__ void k_hin(const int* __restrict__ hloc, const int* __restrict__ htim,
                      const int* __restrict__ counts, const int* __restrict__ offs,
                      const float* __restrict__ emb_loc, const float* __restrict__ emb_tim,
                      ushort* __restrict__ hin) {
  int i = blockIdx.x;
  int tid = threadIdx.x;  // 64
  int off = offs[i], cnt = counts[i];
  float4v s = {0.f, 0.f, 0.f, 0.f};
  for (int e = 0; e < cnt; ++e) {
    int l = hloc[off + e];
    const float4v* row = (const float4v*)(emb_loc + (size_t)l * DL);
    s += row[tid];
  }
  float inv = 1.f / (float)cnt;
  size_t b = (size_t)i * IN3 + tid * 4;
  hin[b + 0] = f2bf(s[0] * inv);
  hin[b + 1] = f2bf(s[1] * inv);
  hin[b + 2] = f2bf(s[2] * inv);
  hin[b + 3] = f2bf(s[3] * inv);
  if (tid < 32) {
    int ht = htim[off];
    hin[(size_t)i * IN3 + 256 + tid] = f2bf(emb_tim[ht * DT + tid]);
  }
}

// ---------------- generic MFMA GEMM: C(MxN) = A(MxK,bf16) @ B(NxK)^T (+bias, act) ----------------
// BF32: B is fp32 (converted to bf16 while staging); ACT: 0 none, 1 tanh
template<bool BF32, int ACT>
__global__ __launch_bounds__(256, 2)
void k_gemm(const ushort* __restrict__ A, const void* __restrict__ Bv,
            const float* __restrict__ bias, float* __restrict__ C,
            int M, int N, int K) {
  __shared__ __align__(16) ushort As[128 * 40];
  __shared__ __align__(16) ushort Bs[128 * 40];
  const int tid = threadIdx.x;
  const int m0 = blockIdx.x * 128;
  const int n0 = blockIdx.y * 128;
  const int wave = tid >> 6, lane = tid & 63;
  const int wm = (wave & 1) << 6, wn = (wave >> 1) << 6;
  const int r16 = lane & 15, kq = lane >> 4;
  floatx4 acc[4][4];
  for (int i = 0; i < 4; i++)
    for (int j = 0; j < 4; j++)
      acc[i][j] = (floatx4){0.f, 0.f, 0.f, 0.f};
  const int srow = tid >> 1;
  const int scol = (tid & 1) << 4;
  const bool bok = (n0 + srow) < N;
  for (int k0 = 0; k0 < K; k0 += 32) {
    const ushort* ap = A + (size_t)(m0 + srow) * K + k0 + scol;
    uint4 a0 = *(const uint4*)ap;
    uint4 a1 = *(const uint4*)(ap + 8);
    *(uint4*)&As[srow * 40 + scol] = a0;
    *(uint4*)&As[srow * 40 + scol + 8] = a1;
    if (BF32) {
      const float* bp = (const float*)Bv + (size_t)(n0 + srow) * K + k0 + scol;
      float4v b0 = {0,0,0,0}, b1 = {0,0,0,0}, b2 = {0,0,0,0}, b3 = {0,0,0,0};
      if (bok) {
        b0 = ((const float4v*)bp)[0];
        b1 = ((const float4v*)bp)[1];
        b2 = ((const float4v*)bp)[2];
        b3 = ((const float4v*)bp)[3];
      }
      ushort8v v0, v1;
      for (int j = 0; j < 4; j++) {
        v0[j] = f2bf(b0[j]); v0[4 + j] = f2bf(b1[j]);
        v1[j] = f2bf(b2[j]); v1[4 + j] = f2bf(b3[j]);
      }
      *(ushort8v*)&Bs[srow * 40 + scol] = v0;
      *(ushort8v*)&Bs[srow * 40 + scol + 8] = v1;
    } else {
      const ushort* bp = (const ushort*)Bv + (size_t)(n0 + srow) * K + k0 + scol;
      uint4 z = {0u, 0u, 0u, 0u};
      uint4 b0 = bok ? *(const uint4*)bp : z;
      uint4 b1 = bok ? *(const uint4*)(bp + 8) : z;
      *(uint4*)&Bs[srow * 40 + scol] = b0;
      *(uint4*)&Bs[srow * 40 + scol + 8] = b1;
    }
    __syncthreads();
    short8 af[4], bfr[4];
    #pragma unroll
    for (int i = 0; i < 4; i++) af[i] = *(const short8*)&As[(wm + i * 16 + r16) * 40 + kq * 8];
    #pragma unroll
    for (int i = 0; i < 4; i++) bfr[i] = *(const short8*)&Bs[(wn + i * 16 + r16) * 40 + kq * 8];
    #pragma unroll
    for (int i = 0; i < 4; i++)
      #pragma unroll
      for (int j = 0; j < 4; j++)
        acc[i][j] = __builtin_amdgcn_mfma_f32_16x16x32_bf16(af[i], bfr[j], acc[i][j], 0, 0, 0);
    __syncthreads();
  }
  #pragma unroll
  for (int j = 0; j < 4; j++) {
    int col = n0 + wn + j * 16 + r16;
    if (col >= N) continue;
    float bv = bias ? bias[col] : 0.f;
    #pragma unroll
    for (int i = 0; i < 4; i++) {
      #pragma unroll
      for (int r = 0; r < 4; r++) {
        int row = m0 + wm + i * 16 + kq * 4 + r;
        float v = acc[i][j][r] + bv;
        if (ACT == 1) v = tanhf(v);
        C[(size_t)row * N + col] = v;
      }
    }
  }
}

// ---------------- history: fp32 -> bf16 and bf16-transposed ----------------
__global__ void k_hist_cast(const float* __restrict__ Hf, ushort* __restrict__ Hb,
                            ushort* __restrict__ HTb) {
  __shared__ float tle[64][65];
  int i0 = blockIdx.x * 64;   // rows over 4096
  int j0 = blockIdx.y * 64;   // cols over 512
  int tid = threadIdx.x;
  #pragma unroll
  for (int rep = 0; rep < 16; ++rep) {
    int idx = rep * 256 + tid;
    int r = idx >> 6, c = idx & 63;
    float v = Hf[(size_t)(i0 + r) * 512 + j0 + c];
    tle[r][c] = v;
    Hb[(size_t)(i0 + r) * 512 + j0 + c] = f2bf(v);
  }
  __syncthreads();
  #pragma unroll
  for (int rep = 0; rep < 16; ++rep) {
    int idx = rep * 256 + tid;
    int r = idx >> 6, c = idx & 63;
    HTb[(size_t)(j0 + r) * 4096 + i0 + c] = f2bf(tle[c][r]);
  }
}

// ---------------- bidirectional GRU via MFMA matvec, one block (1 CU) per direction ----------------
// 512 threads = 8 waves. Wave w owns gate-rows [w*96, w*96+96) of the 768x256 Whh.
// Weights resident in VGPRs as mfma_f32_16x16x32_f16 A-fragments (48 frags = 192 VGPRs).
// h lives in LDS as f16; B-operand column 0 = h chunk (lanes with (lane&15)==0 read 16B,
// all other lanes read a zero page, so C columns 1..15 are garbage we ignore).
__global__ __launch_bounds__(512, 2)
void k_gru(const float* __restrict__ gi_f, const float* __restrict__ gi_b,
           const uint4* __restrict__ wpack,
           const float* __restrict__ bhh_f, const float* __restrict__ bhh_b,
           ushort* __restrict__ qb) {
  const int dir = blockIdx.x;
  const int tid = threadIdx.x;
  const int wave = tid >> 6, lane = tid & 63;
  const float* gi = dir ? gi_b : gi_f;
  const float* bhh = dir ? bhh_b : bhh_f;

  __shared__ __align__(16) _Float16 hbuf[256];
  __shared__ __align__(16) _Float16 zbuf[256];
  __shared__ __align__(16) float ghs[768];

  // ---- load weight fragments into registers (192 VGPRs) ----
  half8v afr[6][8];
  {
    const uint4* wp = wpack + (size_t)dir * 24576 + wave * 3072 + lane;
    #pragma unroll
    for (int rt = 0; rt < 6; ++rt)
      #pragma unroll
      for (int kt = 0; kt < 8; ++kt)
        afr[rt][kt] = __builtin_bit_cast(half8v, wp[rt * 512 + kt * 64]);
  }
  if (tid < 256) { hbuf[tid] = (_Float16)0.f; zbuf[tid] = (_Float16)0.f; }

  // per-lane B-operand source: col-0 lanes read h, others read zeros
  const _Float16* bsrc = ((lane & 15) == 0) ? (hbuf + (lane >> 4) * 8) : zbuf;
  // gh output rows for this lane (col-0 lanes): row = wave*96 + rt*16 + (lane>>4)*4 + r
  const int gw_row = wave * 96 + (lane >> 4) * 4;
  const bool gw_ok = ((lane & 15) == 0);

  const int dim = tid;  // valid for tid < 256
  float b_r = 0.f, b_z = 0.f, b_n = 0.f;
  float gi0 = 0.f, gi1 = 0.f, gi2 = 0.f;
  if (tid < 256) {
    b_r = bhh[dim]; b_z = bhh[256 + dim]; b_n = bhh[512 + dim];
    int t0 = dir ? 2047 : 0;
    gi0 = gi[(size_t)t0 * 768 + dim];
    gi1 = gi[(size_t)t0 * 768 + 256 + dim];
    gi2 = gi[(size_t)t0 * 768 + 512 + dim];
  }
  float h_cur = 0.f;
  __syncthreads();

  for (int s = 0; s < 2048; ++s) {
    // prefetch next step's gi (hidden under the MFMA phase)
    int tn = dir ? (2046 - s) : (s + 1);
    tn = tn < 0 ? 0 : (tn > 2047 ? 2047 : tn);
    float ngi0 = 0.f, ngi1 = 0.f, ngi2 = 0.f;
    if (tid < 256) {
      ngi0 = gi[(size_t)tn * 768 + dim];
      ngi1 = gi[(size_t)tn * 768 + 256 + dim];
      ngi2 = gi[(size_t)tn * 768 + 512 + dim];
    }

    // ---- gh = Whh @ h via MFMA (col 0 of C) ----
    floatx4 acc[6];
    #pragma unroll
    for (int rt = 0; rt < 6; ++rt) acc[rt] = (floatx4){0.f, 0.f, 0.f, 0.f};
    #pragma unroll
    for (int kt = 0; kt < 8; ++kt) {
      half8v b = *(const half8v*)(bsrc + kt * 32);
      #pragma unroll
      for (int rt = 0; rt < 6; ++rt)
        acc[rt] = __builtin_amdgcn_mfma_f32_16x16x32_f16(afr[rt][kt], b, acc[rt], 0, 0, 0);
    }
    if (gw_ok) {
      #pragma unroll
      for (int rt = 0; rt < 6; ++rt)
        *(floatx4*)&ghs[gw_row + rt * 16] = acc[rt];
    }
    __syncthreads();

    // ---- gate nonlinearity + h update (waves 0..3) ----
    if (tid < 256) {
      float gr = ghs[dim] + b_r + gi0;
      float gz = ghs[256 + dim] + b_z + gi1;
      float gn = ghs[512 + dim] + b_n;
      float r = 1.f / (1.f + __expf(-gr));
      float z = 1.f / (1.f + __expf(-gz));
      float x = gi2 + r * gn;
      float nn = 1.f - 2.f / (__expf(2.f * x) + 1.f);
      h_cur = (1.f - z) * nn + z * h_cur;
      hbuf[dim] = (_Float16)h_cur;
      if (dir == 0) {
        if (s >= 1024) qb[(size_t)(s - 1024) * 512 + dim] = f2bf(h_cur);
      } else {
        if (s < 1024) qb[(size_t)(1023 - s) * 512 + 256 + dim] = f2bf(h_cur);
      }
    }
    __syncthreads();
    gi0 = ngi0; gi1 = ngi1; gi2 = ngi2;
  }
}

// ---------------- softmax over 4096 cols -> bf16 probs ----------------
__global__ void k_softmax(const float* __restrict__ S, ushort* __restrict__ P) {
  int m = blockIdx.x;
  int tid = threadIdx.x;
  const float* row = S + (size_t)m * 4096;
  float ev[16];
  float mx = -3.0e38f;
  #pragma unroll
  for (int i = 0; i < 16; i++) {
    float x = row[tid + i * 256];
    ev[i] = x;
    mx = fmaxf(mx, x);
  }
  #pragma unroll
  for (int o = 32; o > 0; o >>= 1) mx = fmaxf(mx, __shfl_xor(mx, o));
  __shared__ float red[4];
  __shared__ float red2[4];
  int w = tid >> 6, l = tid & 63;
  if (l == 0) red[w] = mx;
  __syncthreads();
  mx = fmaxf(fmaxf(red[0], red[1]), fmaxf(red[2], red[3]));
  float sm = 0.f;
  #pragma unroll
  for (int i = 0; i < 16; i++) {
    ev[i] = __expf(ev[i] - mx);
    sm += ev[i];
  }
  #pragma unroll
  for (int o = 32; o > 0; o >>= 1) sm += __shfl_xor(sm, o);
  if (l == 0) red2[w] = sm;
  __syncthreads();
  sm = red2[0] + red2[1] + red2[2] + red2[3];
  float inv = 1.f / sm;
  #pragma unroll
  for (int i = 0; i < 16; i++)
    P[(size_t)m * 4096 + tid + i * 256] = f2bf(ev[i] * inv);
}

// ---------------- assemble out = [q | context | uid_emb] bf16 ----------------
__global__ void k_assemble(const ushort* __restrict__ qb, const float* __restrict__ ctx,
                           const float* __restrict__ emb_uid, const int* __restrict__ uid,
                           ushort* __restrict__ ob) {
  int m = blockIdx.x, tid = threadIdx.x;
  int u = uid[0];
  for (int c = tid; c < DOUT; c += 256) {
    ushort v;
    if (c < 512) v = qb[(size_t)m * 512 + c];
    else if (c < 1024) v = f2bf(ctx[(size_t)m * 512 + (c - 512)]);
    else v = f2bf(emb_uid[(size_t)u * DU + (c - 1024)]);
    ob[(size_t)m * DOUT + c] = v;
  }
}

// ---------------- per-row log-sum-exp over 100000 ----------------
__global__ void k_lse(const float* __restrict__ logits, float* __restrict__ lse) {
  int m = blockIdx.x, tid = threadIdx.x;
  const float* row = logits + (size_t)m * NLOC;
  float mx = -3.0e38f, sm = 0.f;
  for (int c = tid; c < NLOC; c += 256) {
    float x = row[c];
    float nm = fmaxf(mx, x);
    sm = sm * __expf(mx - nm) + __expf(x - nm);
    mx = nm;
  }
  #pragma unroll
  for (int o = 32; o > 0; o >>= 1) {
    float omx = __shfl_xor(mx, o);
    float osm = __shfl_xor(sm, o);
    float nm = fmaxf(mx, omx);
    sm = sm * __expf(mx - nm) + osm * __expf(omx - nm);
    mx = nm;
  }
  __shared__ float smx[4], ssm[4];
  int w = tid >> 6;
  if ((tid & 63) == 0) { smx[w] = mx; ssm[w] = sm; }
  __syncthreads();
  if (tid == 0) {
    float M = fmaxf(fmaxf(smx[0], smx[1]), fmaxf(smx[2], smx[3]));
    float S = ssm[0] * __expf(smx[0] - M) + ssm[1] * __expf(smx[1] - M)
            + ssm[2] * __expf(smx[2] - M) + ssm[3] * __expf(smx[3] - M);
    lse[m] = M + logf(S);
  }
}

// ---------------- out -= lse[row], in-place ----------------
__global__ void k_sub(float* __restrict__ out, const float* __restrict__ lse) {
  int i = blockIdx.x * 256 + threadIdx.x;  // float4 index
  if (i >= TGT * (NLOC / 4)) return;
  int rowq = i / (NLOC / 4);
  float4v v = ((float4v*)out)[i];
  float l = lse[rowq];
  v[0] -= l; v[1] -= l; v[2] -= l; v[3] -= l;
  ((float4v*)out)[i] = v;
}

extern "C" void kernel_launch(void* const* d_in, const int* in_sizes, int n_in,
                              void* d_out, int out_size, void* d_ws, size_t ws_size,
                              hipStream_t stream) {
  const int*   loc     = (const int*)d_in[0];
  const int*   tim     = (const int*)d_in[1];
  const int*   hloc    = (const int*)d_in[2];
  const int*   htim    = (const int*)d_in[3];
  const int*   hcnt    = (const int*)d_in[4];
  const int*   uid     = (const int*)d_in[5];
  const float* emb_loc = (const float*)d_in[7];
  const float* emb_tim = (const float*)d_in[8];
  const float* emb_uid = (const float*)d_in[9];
  const float* W_attn  = (const float*)d_in[10];
  const float* b_attn  = (const float*)d_in[11];
  const float* Wih_f   = (const float*)d_in[12];
  const float* Whh_f   = (const float*)d_in[13];
  const float* bih_f   = (const float*)d_in[14];
  const float* bhh_f   = (const float*)d_in[15];
  const float* Wih_b   = (const float*)d_in[16];
  const float* Whh_b   = (const float*)d_in[17];
  const float* bih_b   = (const float*)d_in[18];
  const float* bhh_b   = (const float*)d_in[19];
  const float* Wf      = (const float*)d_in[20];
  const float* bfv     = (const float*)d_in[21];
  float* out = (float*)d_out;

  char* w = (char*)d_ws;
  size_t o = 0;
  auto take = [&](size_t bytes) -> void* {
    o = (o + 511) & ~(size_t)511;
    void* p = w + o;
    o += bytes;
    return p;
  };
  int*    offs   = (int*)take(4096 * 4);
  ushort* xb     = (ushort*)take((size_t)SEQ * IN3 * 2);
  ushort* hin    = (ushort*)take((size_t)NHIST * IN3 * 2);
  float*  gi_f   = (float*)take((size_t)SEQ * G3 * 4);
  float*  gi_b   = (float*)take((size_t)SEQ * G3 * 4);
  uint4*  wpack  = (uint4*)take((size_t)49152 * sizeof(uint4));
  float*  hist   = (float*)take((size_t)NHIST * 512 * 4);
  ushort* histb  = (ushort*)take((size_t)NHIST * 512 * 2);
  ushort* histTb = (ushort*)take((size_t)512 * NHIST * 2);
  ushort* qb     = (ushort*)take((size_t)TGT * 512 * 2);
  float*  scores = (float*)take((size_t)TGT * NHIST * 4);
  ushort* attnb  = (ushort*)take((size_t)TGT * NHIST * 2);
  float*  ctx    = (float*)take((size_t)TGT * 512 * 4);
  ushort* ob     = (ushort*)take((size_t)TGT * DOUT * 2);
  float*  lsebuf = (float*)take((size_t)TGT * 4);

  // prep
  k_pack_whh<<<192, 256, 0, stream>>>(Whh_f, Whh_b, wpack);
  k_embed_x<<<SEQ, 256, 0, stream>>>(loc, tim, emb_loc, emb_tim, xb);
  k_scan<<<1, 1024, 0, stream>>>(hcnt, offs);
  k_hin<<<NHIST, 64, 0, stream>>>(hloc, htim, hcnt, offs, emb_loc, emb_tim, hin);

  // gi = x @ Wih^T + bih (both directions)
  k_gemm<true, 0><<<dim3(16, 6), 256, 0, stream>>>(xb, (const void*)Wih_f, bih_f, gi_f, SEQ, G3, IN3);
  k_gemm<true, 0><<<dim3(16, 6), 256, 0, stream>>>(xb, (const void*)Wih_b, bih_b, gi_b, SEQ, G3, IN3);

  // history = tanh(Hin @ W_attn^T + b_attn)
  k_gemm<true, 1><<<dim3(32, 4), 256, 0, stream>>>(hin, (const void*)W_attn, b_attn, hist, NHIST, 512, IN3);
  k_hist_cast<<<dim3(64, 8), 256, 0, stream>>>(hist, histb, histTb);

  // GRU (fwd + bwd in parallel) -> q bf16 (1024 x 512)
  k_gru<<<2, 512, 0, stream>>>(gi_f, gi_b, wpack, bhh_f, bhh_b, qb);

  // scores = q @ history^T ; softmax ; context = attn @ history
  k_gemm<false, 0><<<dim3(8, 32), 256, 0, stream>>>(qb, (const void*)histb, nullptr, scores, TGT, NHIST, 512);
  k_softmax<<<TGT, 256, 0, stream>>>(scores, attnb);
  k_gemm<false, 0><<<dim3(8, 4), 256, 0, stream>>>(attnb, (const void*)histTb, nullptr, ctx, TGT, 512, NHIST);

  // out = [q | context | uid_emb]; logits = out @ Wf^T + bf
  k_assemble<<<TGT, 256, 0, stream>>>(qb, ctx, emb_uid, uid, ob);
  k_gemm<true, 0><<<dim3(8, 782), 256, 0, stream>>>(ob, (const void*)Wf, bfv, out, TGT, NLOC, DOUT);

  // log_softmax
  k_lse<<<TGT, 256, 0, stream>>>(out, lsebuf);
  k_sub<<<(TGT * (NLOC / 4) + 255) / 256, 256, 0, stream>>>(out, lsebuf);
}